// Round 16
// baseline (186.273 us; speedup 1.0000x reference)
//
#include <hip/hip_runtime.h>
#include <stdint.h>

#define NG   64      // graphs
#define N0   1024    // nodes layer 1
#define N1   512     // nodes layer 2 (k1)
#define K2   256     // k at layer 2
#define DD   128     // feature dim
#define NE   16384   // edges per graph
#define NOUT 64      // output dim

__device__ __forceinline__ float waveReduceSum(float v) {
    for (int off = 32; off > 0; off >>= 1) v += __shfl_xor(v, off, 64);
    return v;
}

// Hybrid bitonic sort, descending, 1 thread = 1 element (identical to R14).
template<int NN>
__device__ __forceinline__ unsigned long long bitonic_desc(
    unsigned long long key, unsigned long long* lds, int i)
{
    for (int k2 = 2; k2 <= NN; k2 <<= 1) {
        for (int j = k2 >> 1; j > 0; j >>= 1) {
            unsigned long long p;
            if (j >= 64) {
                __syncthreads();
                lds[i] = key;
                __syncthreads();
                p = lds[i ^ j];
            } else {
                p = __shfl_xor(key, j, 64);
            }
            bool keepMax = (((i & k2) == 0) == ((i & j) == 0));
            if (keepMax ? (p > key) : (p < key)) key = p;
        }
    }
    return key;
}

__device__ __forceinline__ unsigned long long make_key(float attnv, float sgn, int i, int nn) {
    float sc = tanhf(attnv * sgn);
    unsigned int u = __float_as_uint(sc);
    u = (u & 0x80000000u) ? ~u : (u | 0x80000000u);
    return ((unsigned long long)u << 32) | (unsigned int)(nn - 1 - i);
}

// ---------------------------------------------------------------------------
// K1: wide dots (4096 blocks) + zero the agg accumulators for both layers.
// ---------------------------------------------------------------------------
__global__ __launch_bounds__(256) void dots_all_kernel(
    const float* __restrict__ x,
    const float* __restrict__ w_rel, const float* __restrict__ w_root,
    const float* __restrict__ b_rel,
    float* __restrict__ s_rel1, float* __restrict__ attn1,
    float* __restrict__ s_rel2f, float* __restrict__ s_root2f,
    float* __restrict__ agg1,   // (G*N0) zeroed here
    float* __restrict__ agg2,   // (G*N1) zeroed here
    int totalNodes)
{
    int wave = blockIdx.x * 4 + (threadIdx.x >> 6);
    int lane = threadIdx.x & 63;
    // zero agg slices (this kernel finishes before any scatter kernel runs)
    int gid = blockIdx.x * 256 + threadIdx.x;
    if (gid < NG * N0) agg1[gid] = 0.f;
    if (gid < NG * N1) agg2[gid] = 0.f;

    float wr10 = w_rel[lane * 2],       wr11 = w_rel[lane * 2 + 1];
    float wo10 = w_root[lane * 2],      wo11 = w_root[lane * 2 + 1];
    float wr20 = w_rel[DD + lane * 2],  wr21 = w_rel[DD + lane * 2 + 1];
    float wo20 = w_root[DD + lane * 2], wo21 = w_root[DD + lane * 2 + 1];
    float b0 = b_rel[0];
    #pragma unroll
    for (int t = 0; t < 4; ++t) {
        int node = wave * 4 + t;
        if (node >= totalNodes) return;
        const float2 v = *(const float2*)(x + (size_t)node * DD + lane * 2);
        float p1 = waveReduceSum(v.x * wr10 + v.y * wr11);
        float p2 = waveReduceSum(v.x * wo10 + v.y * wo11);
        float p3 = waveReduceSum(v.x * wr20 + v.y * wr21);
        float p4 = waveReduceSum(v.x * wo20 + v.y * wo21);
        if (lane == 0) {
            s_rel1[node]   = p1;
            attn1[node]    = p2 + b0;
            s_rel2f[node]  = p3;
            s_root2f[node] = p4;
        }
    }
}

// ---------------------------------------------------------------------------
// K2: wide layer-1 scatter. 1024 blocks x 256 thr x 4 edges. Global atomics
// into agg1 (L2 atomic units, all XCDs). agg1/s_rel1 are L2-resident (256KB).
// ---------------------------------------------------------------------------
__global__ __launch_bounds__(256) void scatter1_kernel(
    const int* __restrict__ ei,          // (G, 2, NE)
    const float* __restrict__ s_rel1,    // (G*N0)
    float* __restrict__ agg1)            // (G*N0)
{
    int e4 = blockIdx.x * 256 + threadIdx.x;      // 0 .. 262143
    int e  = e4 * 4;
    int g  = e >> 14, eo = e & (NE - 1);
    const int* base = ei + (size_t)g * 2 * NE;
    const int4 s4 = *(const int4*)(base + eo);
    const int4 d4 = *(const int4*)(base + NE + eo);
    const float* sr = s_rel1 + (g << 10);
    float* ag = agg1 + (g << 10);
    atomicAdd(&ag[d4.x], sr[s4.x]);
    atomicAdd(&ag[d4.y], sr[s4.y]);
    atomicAdd(&ag[d4.z], sr[s4.z]);
    atomicAdd(&ag[d4.w], sr[s4.w]);
}

// ---------------------------------------------------------------------------
// K3: per-graph layer-1 sort + select (sort identical to R14). No scatter.
// ---------------------------------------------------------------------------
__global__ __launch_bounds__(1024) void graph1_kernel(
    const float* __restrict__ attn1,     // (G*N0) root+bias
    const float* __restrict__ agg1,      // (G*N0) edge sums
    const float* __restrict__ s_rel2f,   // (G*N0)
    const float* __restrict__ s_root2f,  // (G*N0)
    const float* __restrict__ b_rel,     // (2,)
    const float* __restrict__ w_sel,     // (2,)
    int*   __restrict__ perm1,           // (G, N1)
    float* __restrict__ tops1,           // (G, N1)
    int*   __restrict__ newidx1,         // (G, N0)
    float* __restrict__ srel2out,        // (G, N1)
    float* __restrict__ attn2out)        // (G, N1)
{
    __shared__ unsigned long long keys[N0];
    const int g = blockIdx.x, i = threadIdx.x;

    float attnv = attn1[(size_t)g * N0 + i] + agg1[(size_t)g * N0 + i];
    const float sgn = (w_sel[0] >= 0.f) ? 1.f : -1.f;
    unsigned long long key = make_key(attnv, sgn, i, N0);
    key = bitonic_desc<N0>(key, keys, i);

    int idx = (N0 - 1) - (int)(key & 0xffffffffu);
    unsigned int ku = (unsigned int)(key >> 32);
    unsigned int fb = (ku & 0x80000000u) ? (ku ^ 0x80000000u) : ~ku;
    newidx1[(size_t)g * N0 + idx] = (i < N1) ? i : -1;
    if (i < N1) {
        float t = __uint_as_float(fb);
        perm1[(size_t)g * N1 + i] = idx;
        tops1[(size_t)g * N1 + i] = t;
        srel2out[(size_t)g * N1 + i] = t * s_rel2f[(size_t)g * N0 + idx];
        attn2out[(size_t)g * N1 + i] = t * s_root2f[(size_t)g * N0 + idx] + b_rel[1];
    }
}

// ---------------------------------------------------------------------------
// K4: wide layer-2 scatter: remap via newidx1 (L2-resident) + global atomics.
// ---------------------------------------------------------------------------
__global__ __launch_bounds__(256) void scatter2_kernel(
    const int* __restrict__ ei,          // (G, 2, NE)
    const int* __restrict__ newidx1,     // (G*N0)
    const float* __restrict__ srel2,     // (G*N1)
    float* __restrict__ agg2)            // (G*N1)
{
    int e4 = blockIdx.x * 256 + threadIdx.x;
    int e  = e4 * 4;
    int g  = e >> 14, eo = e & (NE - 1);
    const int* base = ei + (size_t)g * 2 * NE;
    const int4 s4 = *(const int4*)(base + eo);
    const int4 d4 = *(const int4*)(base + NE + eo);
    const int* ni = newidx1 + (g << 10);
    const float* sr = srel2 + (g << 9);
    float* ag = agg2 + (g << 9);
    int s2, d2;
    s2 = ni[s4.x]; d2 = ni[d4.x]; if ((s2 | d2) >= 0) atomicAdd(&ag[d2], sr[s2]);
    s2 = ni[s4.y]; d2 = ni[d4.y]; if ((s2 | d2) >= 0) atomicAdd(&ag[d2], sr[s2]);
    s2 = ni[s4.z]; d2 = ni[d4.z]; if ((s2 | d2) >= 0) atomicAdd(&ag[d2], sr[s2]);
    s2 = ni[s4.w]; d2 = ni[d4.w]; if ((s2 | d2) >= 0) atomicAdd(&ag[d2], sr[s2]);
}

// ---------------------------------------------------------------------------
// K5: per-graph layer-2 padded sort (identical to R14) + fused readout+GEMV.
// ---------------------------------------------------------------------------
__global__ __launch_bounds__(1024) void graph2_readout_kernel(
    const float* __restrict__ x0,        // (G, N0, D)
    const int*   __restrict__ perm1,     // (G, N1)
    const float* __restrict__ tops1,     // (G, N1)
    const float* __restrict__ attn2b,    // (G, N1) root part
    const float* __restrict__ agg2,      // (G, N1) edge sums
    const float* __restrict__ w_sel,     // (2,)
    const float* __restrict__ W_lin,     // (2D, OUT)
    const float* __restrict__ b_lin,     // (OUT)
    float* __restrict__ out)             // (G, OUT)
{
    __shared__ unsigned long long keys[N0];
    __shared__ int   p1l[N1];
    __shared__ float t1l[N1];
    __shared__ int   cn0[K2];
    __shared__ float cs[K2];
    __shared__ float sm[4][DD], mm[4][DD], rr[2 * DD], po[4][NOUT];

    const int g = blockIdx.x, i = threadIdx.x;
    const float* xg = x0 + (size_t)g * N0 * DD;
    if (i < N1) {
        p1l[i] = perm1[(size_t)g * N1 + i];
        t1l[i] = tops1[(size_t)g * N1 + i];
    }

    // padded sort: 512 real keys + 512 zero pads (pads sink; verified R9)
    {
        const float sgn = (w_sel[1] >= 0.f) ? 1.f : -1.f;
        unsigned long long key = 0ULL;
        if (i < N1) {
            float attnv = attn2b[(size_t)g * N1 + i] + agg2[(size_t)g * N1 + i];
            key = make_key(attnv, sgn, i, N1);
        }
        key = bitonic_desc<N0>(key, keys, i);
        if (i < K2) {
            int idx = (N1 - 1) - (int)(key & 0xffffffffu);
            unsigned int ku = (unsigned int)(key >> 32);
            unsigned int fb = (ku & 0x80000000u) ? (ku ^ 0x80000000u) : ~ku;
            cn0[i] = p1l[idx];                        // composed node in x0
            cs[i]  = __uint_as_float(fb) * t1l[idx];  // composed scale
        }
    }
    __syncthreads();

    // readout: mean/max over 256 rows of x0[cn0[j]] * cs[j] (R8/R9 tree)
    if (i < 512) {
        const int d = i & (DD - 1), q = i >> 7;
        float sum = 0.f, mx = -3.0e38f;
        #pragma unroll 4
        for (int j = q * 64; j < q * 64 + 64; ++j) {
            float v = xg[(size_t)cn0[j] * DD + d] * cs[j];
            sum += v;
            mx = fmaxf(mx, v);
        }
        sm[q][d] = sum; mm[q][d] = mx;
    }
    __syncthreads();
    if (i < DD) {
        rr[i] = (sm[0][i] + sm[1][i] + sm[2][i] + sm[3][i]) * (1.f / 256.f);
    } else if (i < 2 * DD) {
        int dd = i - DD;
        rr[DD + dd] = fmaxf(fmaxf(mm[0][dd], mm[1][dd]), fmaxf(mm[2][dd], mm[3][dd]));
    }
    __syncthreads();
    if (i < 256) {
        int o = i & (NOUT - 1), c = i >> 6;
        float acc = 0.f;
        #pragma unroll
        for (int i2 = 0; i2 < 64; ++i2) {
            int ii = c * 64 + i2;
            acc += rr[ii] * W_lin[ii * NOUT + o];
        }
        po[c][o] = acc;
    }
    __syncthreads();
    if (i < NOUT)
        out[(size_t)g * NOUT + i] =
            b_lin[i] + po[0][i] + po[1][i] + po[2][i] + po[3][i];
}

// ---------------------------------------------------------------------------
extern "C" void kernel_launch(void* const* d_in, const int* in_sizes, int n_in,
                              void* d_out, int out_size, void* d_ws, size_t ws_size,
                              hipStream_t stream)
{
    const float* x0     = (const float*)d_in[0];  // (G, 1024, 128)
    const int*   ei     = (const int*)  d_in[1];  // (G, 2, E)
    const float* w_rel  = (const float*)d_in[2];  // (2, 128)
    const float* b_rel  = (const float*)d_in[3];  // (2,)
    const float* w_root = (const float*)d_in[4];  // (2, 128)
    const float* w_sel  = (const float*)d_in[5];  // (2,)
    const float* W_lin  = (const float*)d_in[6];  // (256, 64)
    const float* b_lin  = (const float*)d_in[7];  // (64,)
    float* out = (float*)d_out;
    (void)in_sizes; (void)n_in; (void)out_size; (void)ws_size;

    char* ws = (char*)d_ws;
    size_t off = 0;
    auto alloc = [&](size_t bytes) -> void* {
        off = (off + 255) & ~(size_t)255;
        void* p = ws + off;
        off += bytes;
        return p;
    };

    float* s_rel1   = (float*)alloc((size_t)NG * N0 * 4);
    float* attn1    = (float*)alloc((size_t)NG * N0 * 4);
    float* s_rel2f  = (float*)alloc((size_t)NG * N0 * 4);
    float* s_root2f = (float*)alloc((size_t)NG * N0 * 4);
    float* agg1     = (float*)alloc((size_t)NG * N0 * 4);
    float* agg2     = (float*)alloc((size_t)NG * N1 * 4);
    int*   perm1    = (int*)  alloc((size_t)NG * N1 * 4);
    float* tops1    = (float*)alloc((size_t)NG * N1 * 4);
    int*   newidx1  = (int*)  alloc((size_t)NG * N0 * 4);
    float* srel2    = (float*)alloc((size_t)NG * N1 * 4);
    float* attn2b   = (float*)alloc((size_t)NG * N1 * 4);

    dots_all_kernel<<<(NG * N0) / 16, 256, 0, stream>>>(
        x0, w_rel, w_root, b_rel, s_rel1, attn1, s_rel2f, s_root2f,
        agg1, agg2, NG * N0);

    scatter1_kernel<<<(NG * NE) / 1024, 256, 0, stream>>>(ei, s_rel1, agg1);

    graph1_kernel<<<NG, 1024, 0, stream>>>(
        attn1, agg1, s_rel2f, s_root2f, b_rel, w_sel,
        perm1, tops1, newidx1, srel2, attn2b);

    scatter2_kernel<<<(NG * NE) / 1024, 256, 0, stream>>>(
        ei, newidx1, srel2, agg2);

    graph2_readout_kernel<<<NG, 1024, 0, stream>>>(
        x0, perm1, tops1, attn2b, agg2, w_sel, W_lin, b_lin, out);
}